// Round 9
// baseline (590.616 us; speedup 1.0000x reference)
//
#include <hip/hip_runtime.h>

// FPS: dense pass + ONE block per batch for all remaining steps.
// B=64, N=262144, NPOINT=10.
// Dense: full scan vs point 0 -> per-chunk (max, first-argmax) = UBs.
// Finish (64 blocks x 1024 thr): per batch, 8 iterations, each:
//   wave0: cand-refresh (1 exact dist per chunk) -> LB = max cand,
//          survivor list (staleUB >= LB, strict <) via 64-bit ballot;
//   all 16 waves: parallel exact rescans of survivor quarter-chunks;
//   wave0: combine, update state, winner = (max val, lowest idx).
// No atomics, no cross-block comm -> bit-deterministic. 2 launches.

#define NPOINT 10
#define NB     64
#define NPTS   262144
#define G      64            // 4096-pt chunks per batch
#define CH     4096
#define QCH    1024          // quarter-chunk (one wave-task)
#define TPB_A  256
#define PPT_A  16
#define TPB_B  1024
#define WPB_B  16
#define LPT    16            // pts per lane per quarter scan
#define INIT_DIST 1e10f

// Strict IEEE, reference association order ((dx^2+dy^2)+dz^2), no contraction.
__device__ __forceinline__ float sqdist(float x, float y, float z,
                                        float cx, float cy, float cz) {
    float dx = x - cx, dy = y - cy, dz = z - cz;
    return __fadd_rn(__fadd_rn(__fmul_rn(dx, dx), __fmul_rn(dy, dy)),
                     __fmul_rn(dz, dz));
}

// 64-lane shfl argmax (max val, ties -> lowest idx); result in lane 0.
__device__ __forceinline__ void wave_argmax(float& v, int& i) {
    #pragma unroll
    for (int off = 32; off > 0; off >>= 1) {
        float ov = __shfl_down(v, off); int oi = __shfl_down(i, off);
        if (ov > v || (ov == v && oi < i)) { v = ov; i = oi; }
    }
}

// ---- Kernel A: full scan vs point 0 -> per-chunk (max, first-argmax).
__global__ __launch_bounds__(TPB_A) void fps_scan1(
    const float* __restrict__ xyz,
    float* __restrict__ ub, int* __restrict__ uidx)
{
    const int b = blockIdx.y, g = blockIdx.x, tid = threadIdx.x;
    const int lane = tid & 63, wv = tid >> 6;
    const float* xyzb = xyz + (size_t)b * NPTS * 3;
    const float cx = xyzb[0], cy = xyzb[1], cz = xyzb[2];
    __shared__ float s_v[4];
    __shared__ int   s_i[4];

    float bestv = -1.0f; int besti = 0;
    const int p0 = g * CH + tid * PPT_A;
    #pragma unroll
    for (int grp = 0; grp < PPT_A / 4; ++grp) {
        const float4* src = (const float4*)(xyzb + (size_t)(p0 + grp * 4) * 3);
        float4 a = src[0], c4 = src[1], e = src[2];
        float px[4] = {a.x, a.w, c4.z, e.y};
        float py[4] = {a.y, c4.x, c4.w, e.z};
        float pz[4] = {a.z, c4.y, e.x, e.w};
        #pragma unroll
        for (int j = 0; j < 4; ++j) {
            float d = fminf(INIT_DIST, sqdist(px[j], py[j], pz[j], cx, cy, cz));
            if (d > bestv) { bestv = d; besti = p0 + grp * 4 + j; }
        }
    }
    wave_argmax(bestv, besti);
    if (lane == 0) { s_v[wv] = bestv; s_i[wv] = besti; }
    __syncthreads();
    if (tid == 0) {
        float v = s_v[0]; int i = s_i[0];
        #pragma unroll
        for (int w = 1; w < 4; ++w) {
            float ov = s_v[w]; int oi = s_i[w];
            if (ov > v || (ov == v && oi < i)) { v = ov; i = oi; }
        }
        ub[b * G + g] = v; uidx[b * G + g] = i;
    }
}

// Wave-level exact scan of quarter-chunk qc vs centers 0..K-1; lane0 result.
template <int K>
__device__ __forceinline__ void scanq(const float* __restrict__ xyzb, int qc,
                                      int lane, const float* scx,
                                      const float* scy, const float* scz,
                                      float& outv, int& outi) {
    float cx[K], cy[K], cz[K];
    #pragma unroll
    for (int k = 0; k < K; ++k) { cx[k] = scx[k]; cy[k] = scy[k]; cz[k] = scz[k]; }
    float bestv = -1.0f; int besti = 0;
    const int p0 = qc * QCH + lane * LPT;
    #pragma unroll
    for (int grp = 0; grp < LPT / 4; ++grp) {
        const float4* src = (const float4*)(xyzb + (size_t)(p0 + grp * 4) * 3);
        float4 a = src[0], c4 = src[1], e = src[2];
        float px[4] = {a.x, a.w, c4.z, e.y};
        float py[4] = {a.y, c4.x, c4.w, e.z};
        float pz[4] = {a.z, c4.y, e.x, e.w};
        #pragma unroll
        for (int j = 0; j < 4; ++j) {
            float dmin = INIT_DIST;
            #pragma unroll
            for (int k = 0; k < K; ++k)
                dmin = fminf(dmin, sqdist(px[j], py[j], pz[j], cx[k], cy[k], cz[k]));
            if (dmin > bestv) { bestv = dmin; besti = p0 + grp * 4 + j; }
        }
    }
    wave_argmax(bestv, besti);
    outv = bestv; outi = besti;
}

// ---- Kernel B: one block per batch, steps 2..9, no atomics.
__global__ __launch_bounds__(TPB_B, 1) void fps_finish(
    const float* __restrict__ xyz,
    const float* __restrict__ ub_g, const int* __restrict__ uidx_g,
    int* __restrict__ out)
{
    const int b = blockIdx.x, tid = threadIdx.x;
    const int lane = tid & 63, wv = tid >> 6;
    const float* xyzb = xyz + (size_t)b * NPTS * 3;

    __shared__ float scx[NPOINT], scy[NPOINT], scz[NPOINT];
    __shared__ float l_ub[G], l_cd[G];
    __shared__ int   l_ui[G];
    __shared__ unsigned long long s_mask;
    __shared__ int   s_M, s_slist[G];
    __shared__ float qv[4 * G];
    __shared__ int   qi[4 * G];

    // init: load chunk state; out[0], out[1]; centers 0,1.
    if (wv == 0) {
        float u = ub_g[b * G + lane];
        int  ui = uidx_g[b * G + lane];
        l_ub[lane] = u; l_cd[lane] = u; l_ui[lane] = ui;
        float v = u; int i = ui;
        wave_argmax(v, i);
        if (lane == 0) {
            scx[0] = xyzb[0]; scy[0] = xyzb[1]; scz[0] = xyzb[2];
            out[b * NPOINT + 0] = 0;
            out[b * NPOINT + 1] = i;
            const float* pp = xyzb + (size_t)i * 3;
            scx[1] = pp[0]; scy[1] = pp[1]; scz[1] = pp[2];
        }
    }
    __syncthreads();

    for (int k = 2; k < NPOINT; ++k) {       // centers 0..k-1 -> out[k]
        // phase 1 (wave 0): cand refresh, LB, survivor list
        if (wv == 0) {
            int pi = l_ui[lane];
            const float* pp = xyzb + (size_t)pi * 3;
            float cd = fminf(l_cd[lane],
                             sqdist(pp[0], pp[1], pp[2],
                                    scx[k - 1], scy[k - 1], scz[k - 1]));
            l_cd[lane] = cd;
            float v = cd; int i = pi;
            wave_argmax(v, i);
            float lb = __shfl(v, 0);
            bool flag = (l_ub[lane] >= lb);  // strict < prunes; ties survive
            unsigned long long m = __ballot(flag);
            int pos = __popcll(m & ((1ull << lane) - 1ull));
            if (flag) s_slist[pos] = lane;
            if (lane == 0) { s_mask = m; s_M = (int)__popcll(m); }
        }
        __syncthreads();
        const int nt = 4 * s_M;

        // phase 2 (all waves): parallel quarter-chunk rescans
        for (int t = wv; t < nt; t += WPB_B) {
            const int c = s_slist[t >> 2], qq = t & 3;
            float v; int i;
            switch (k) {
                case 2: scanq<2>(xyzb, c * 4 + qq, lane, scx, scy, scz, v, i); break;
                case 3: scanq<3>(xyzb, c * 4 + qq, lane, scx, scy, scz, v, i); break;
                case 4: scanq<4>(xyzb, c * 4 + qq, lane, scx, scy, scz, v, i); break;
                case 5: scanq<5>(xyzb, c * 4 + qq, lane, scx, scy, scz, v, i); break;
                case 6: scanq<6>(xyzb, c * 4 + qq, lane, scx, scy, scz, v, i); break;
                case 7: scanq<7>(xyzb, c * 4 + qq, lane, scx, scy, scz, v, i); break;
                case 8: scanq<8>(xyzb, c * 4 + qq, lane, scx, scy, scz, v, i); break;
                default: scanq<9>(xyzb, c * 4 + qq, lane, scx, scy, scz, v, i); break;
            }
            if (lane == 0) { qv[t] = v; qi[t] = i; }
        }
        __syncthreads();

        // phase 3 (wave 0): combine quarters, update state, pick winner
        if (wv == 0) {
            float val; int idx;
            const bool flag = (s_mask >> lane) & 1ull;
            if (flag) {
                int pos = (int)__popcll(s_mask & ((1ull << lane) - 1ull));
                float v = qv[4 * pos]; int i = qi[4 * pos];
                #pragma unroll
                for (int qq = 1; qq < 4; ++qq) {   // ascending idx ranges
                    float ov = qv[4 * pos + qq]; int oi = qi[4 * pos + qq];
                    if (ov > v || (ov == v && oi < i)) { v = ov; i = oi; }
                }
                l_ub[lane] = v; l_cd[lane] = v; l_ui[lane] = i;
                val = v; idx = i;
            } else {
                val = l_cd[lane]; idx = l_ui[lane];  // < winner, never ties it
            }
            wave_argmax(val, idx);
            if (lane == 0) {
                out[b * NPOINT + k] = idx;
                const float* pp = xyzb + (size_t)idx * 3;
                scx[k] = pp[0]; scy[k] = pp[1]; scz[k] = pp[2];
            }
        }
        __syncthreads();
    }
}

extern "C" void kernel_launch(void* const* d_in, const int* in_sizes, int n_in,
                              void* d_out, int out_size, void* d_ws, size_t ws_size,
                              hipStream_t stream) {
    const float* xyz = (const float*)d_in[0];
    int* out = (int*)d_out;
    char* ws = (char*)d_ws;

    float* ub   = (float*)(ws + 0);       // 64*64*4 = 16 KB, fully rewritten
    int*   uidx = (int*)  (ws + 16384);   // 16 KB, fully rewritten

    fps_scan1<<<dim3(G, NB), dim3(TPB_A), 0, stream>>>(xyz, ub, uidx);
    fps_finish<<<dim3(NB), dim3(TPB_B), 0, stream>>>(xyz, ub, uidx, out);
}

// Round 10
// 192.310 us; speedup vs baseline: 3.0712x; 3.0712x over previous
//
#include <hip/hip_runtime.h>

// FPS, multi-launch with gather-free records + quarter-granularity pruning.
// B=64, N=262144, NPOINT=10. Records per quarter (1024 pts), 256/batch:
//   ub   = stale chunk max (monotone-valid upper bound)
//   cand = EXACT current min-dist of point uidx (sequential fminf fold,
//          same association order as reference -> bit-exact)
//   uidx, px,py,pz = the candidate point and its coords (NO gathers needed)
// Step R kernel (64x64 blocks x 256 thr): refresh all 256 cands from
// contiguous records -> LB = max cand (realized value => valid LB);
// each block tests its 4 quarters: staleUB < LB (strict) -> pass record
// through; else exact rescan (4 pts/thread), update record, atomicMax
// packed (valbits<<32)|(~idx) winner -> max val, lowest idx, deterministic.

#define NPOINT 10
#define NB     64
#define NPTS   262144
#define QN     256          // quarters per batch
#define QCH    1024         // points per quarter
#define TPB    256
#define GB     64           // blocks per batch (4 quarters each)
#define INIT_DIST 1e10f

// Strict IEEE, reference association order ((dx^2+dy^2)+dz^2), no contraction.
__device__ __forceinline__ float sqdist(float x, float y, float z,
                                        float cx, float cy, float cz) {
    float dx = x - cx, dy = y - cy, dz = z - cz;
    return __fadd_rn(__fadd_rn(__fmul_rn(dx, dx), __fmul_rn(dy, dy)),
                     __fmul_rn(dz, dz));
}

__device__ __forceinline__ unsigned long long packvi(float v, int i) {
    return ((unsigned long long)__float_as_uint(v) << 32) |
           (unsigned)(0xFFFFFFFFu - (unsigned)i);
}
__device__ __forceinline__ int unpack_idx(unsigned long long w) {
    return (int)(0xFFFFFFFFu - (unsigned)(w & 0xFFFFFFFFull));
}

// 64-lane shfl argmax (max val, ties -> lowest idx); result in lane 0.
__device__ __forceinline__ void wave_argmax(float& v, int& i) {
    #pragma unroll
    for (int off = 32; off > 0; off >>= 1) {
        float ov = __shfl_down(v, off); int oi = __shfl_down(i, off);
        if (ov > v || (ov == v && oi < i)) { v = ov; i = oi; }
    }
}

// ---- Kernel A: full scan vs point 0 -> fresh quarter records + win[1].
__global__ __launch_bounds__(TPB) void fps_scan1(
    const float* __restrict__ xyz, int* __restrict__ out,
    float4* __restrict__ sel,
    float* __restrict__ ub, float* __restrict__ cd, int* __restrict__ ui,
    float* __restrict__ px, float* __restrict__ py, float* __restrict__ pz,
    unsigned long long* __restrict__ win)
{
    const int c = blockIdx.x, b = blockIdx.y, tid = threadIdx.x;
    const int lane = tid & 63, wv = tid >> 6;
    const float* xyzb = xyz + (size_t)b * NPTS * 3;
    const float c0x = xyzb[0], c0y = xyzb[1], c0z = xyzb[2];
    __shared__ float s_v[4];
    __shared__ int   s_i[4];

    const int p0 = c * QCH + tid * 4;
    const float4* src = (const float4*)(xyzb + (size_t)p0 * 3);
    float4 a = src[0], m = src[1], e = src[2];
    float X[4] = {a.x, a.w, m.z, e.y};
    float Y[4] = {a.y, m.x, m.w, e.z};
    float Z[4] = {a.z, m.y, e.x, e.w};
    float bv = -1.0f; int bi = 0;
    #pragma unroll
    for (int j = 0; j < 4; ++j) {
        float d = fminf(INIT_DIST, sqdist(X[j], Y[j], Z[j], c0x, c0y, c0z));
        if (d > bv) { bv = d; bi = p0 + j; }
    }
    wave_argmax(bv, bi);
    if (lane == 0) { s_v[wv] = bv; s_i[wv] = bi; }
    __syncthreads();
    if (tid == 0) {
        float v = s_v[0]; int i = s_i[0];
        #pragma unroll
        for (int w = 1; w < 4; ++w) {
            float ov = s_v[w]; int oi = s_i[w];
            if (ov > v || (ov == v && oi < i)) { v = ov; i = oi; }
        }
        const int o = b * QN + c;
        ub[o] = v; cd[o] = v; ui[o] = i;
        const float* qq = xyzb + (size_t)i * 3;
        px[o] = qq[0]; py[o] = qq[1]; pz[o] = qq[2];
        atomicMax(win + (size_t)1 * NB * 16 + b * 16, packvi(v, i));
        if (c == 0) {
            out[b * NPOINT + 0] = 0;
            sel[b * NPOINT + 0] = make_float4(c0x, c0y, c0z, 0.f);
        }
    }
}

// ---- Kernel B: one FPS step. Block g owns quarters 4g..4g+3.
template <int R>
__global__ __launch_bounds__(TPB) void fps_step(
    const float* __restrict__ xyz, int* __restrict__ out,
    float4* __restrict__ sel,
    const float* __restrict__ ub_i, const float* __restrict__ cd_i,
    const int* __restrict__ ui_i, const float* __restrict__ px_i,
    const float* __restrict__ py_i, const float* __restrict__ pz_i,
    float* __restrict__ ub_o, float* __restrict__ cd_o, int* __restrict__ ui_o,
    float* __restrict__ px_o, float* __restrict__ py_o, float* __restrict__ pz_o,
    unsigned long long* __restrict__ win)
{
    const int g = blockIdx.x, b = blockIdx.y, tid = threadIdx.x;
    const int lane = tid & 63, wv = tid >> 6;
    const float* xyzb = xyz + (size_t)b * NPTS * 3;
    const int boff = b * QN;

    __shared__ float scx[NPOINT], scy[NPOINT], scz[NPOINT];
    __shared__ float s_r[4], s_qub[4];
    __shared__ float s_v[4];
    __shared__ int   s_i[4];

    // resolve winner of step R-1 (uniform), center R-1
    const unsigned long long w = win[(size_t)(R - 1) * NB * 16 + b * 16];
    const int prevIdx = unpack_idx(w);
    const float* pp = xyzb + (size_t)prevIdx * 3;
    const float pcx = pp[0], pcy = pp[1], pcz = pp[2];

    if (tid < R - 1) {
        float4 q = sel[b * NPOINT + tid];
        scx[tid] = q.x; scy[tid] = q.y; scz[tid] = q.z;
    }
    if (tid == 0) { scx[R - 1] = pcx; scy[R - 1] = pcy; scz[R - 1] = pcz; }

    // gather-free cand refresh: thread tid owns record tid (contiguous loads)
    float myub = ub_i[boff + tid];
    float mycd = cd_i[boff + tid];
    int   myui = ui_i[boff + tid];
    float mx = px_i[boff + tid], my = py_i[boff + tid], mz = pz_i[boff + tid];
    mycd = fminf(mycd, sqdist(mx, my, mz, pcx, pcy, pcz));

    // LB = max refreshed cand (value-only block reduce)
    float rv = mycd;
    #pragma unroll
    for (int off = 32; off > 0; off >>= 1)
        rv = fmaxf(rv, __shfl_down(rv, off));
    if (lane == 0) s_r[wv] = rv;
    const int dq = tid - 4 * g;                 // this block's 4 quarter ubs
    if (dq >= 0 && dq < 4) s_qub[dq] = myub;
    __syncthreads();
    const float LB = fmaxf(fmaxf(s_r[0], s_r[1]), fmaxf(s_r[2], s_r[3]));

    if (g == 0 && tid == 0) {                   // bookkeeping (no same-kernel readers)
        out[b * NPOINT + (R - 1)] = prevIdx;
        sel[b * NPOINT + (R - 1)] = make_float4(pcx, pcy, pcz, 0.f);
    }

    // pass-through for pruned quarters (owner thread has the record in regs)
    const bool mine = (dq >= 0 && dq < 4);
    const bool my_survives = mine && (myub >= LB);
    if (mine && !my_survives) {
        ub_o[boff + tid] = myub; cd_o[boff + tid] = mycd; ui_o[boff + tid] = myui;
        px_o[boff + tid] = mx;   py_o[boff + tid] = my;   pz_o[boff + tid] = mz;
    }

    unsigned long long* const wr = win + (size_t)R * NB * 16 + b * 16;
    #pragma unroll
    for (int j = 0; j < 4; ++j) {
        if (s_qub[j] < LB) continue;            // strict: ties stay scannable
        const int q = 4 * g + j;
        const int p0 = q * QCH + tid * 4;
        const float4* src = (const float4*)(xyzb + (size_t)p0 * 3);
        float4 a = src[0], m4 = src[1], e = src[2];
        float X[4] = {a.x, a.w, m4.z, e.y};
        float Y[4] = {a.y, m4.x, m4.w, e.z};
        float Z[4] = {a.z, m4.y, e.x, e.w};
        float bv = -1.0f; int bi = 0;
        #pragma unroll
        for (int t = 0; t < 4; ++t) {
            float dmin = INIT_DIST;
            #pragma unroll
            for (int k = 0; k < R; ++k)
                dmin = fminf(dmin, sqdist(X[t], Y[t], Z[t], scx[k], scy[k], scz[k]));
            if (dmin > bv) { bv = dmin; bi = p0 + t; }
        }
        wave_argmax(bv, bi);
        if (lane == 0) { s_v[wv] = bv; s_i[wv] = bi; }
        __syncthreads();
        if (tid == 0) {
            float v = s_v[0]; int i = s_i[0];
            #pragma unroll
            for (int u = 1; u < 4; ++u) {
                float ov = s_v[u]; int oi = s_i[u];
                if (ov > v || (ov == v && oi < i)) { v = ov; i = oi; }
            }
            const float* qq = xyzb + (size_t)i * 3;
            ub_o[boff + q] = v; cd_o[boff + q] = v; ui_o[boff + q] = i;
            px_o[boff + q] = qq[0]; py_o[boff + q] = qq[1]; pz_o[boff + q] = qq[2];
            atomicMax(wr, packvi(v, i));
        }
        __syncthreads();
    }
}

// ---- Final: decode step-9 winners.
__global__ __launch_bounds__(64) void fps_final(
    const unsigned long long* __restrict__ win, int* __restrict__ out)
{
    const int b = threadIdx.x;
    if (b < NB)
        out[b * NPOINT + (NPOINT - 1)] =
            unpack_idx(win[(size_t)(NPOINT - 1) * NB * 16 + b * 16]);
}

extern "C" void kernel_launch(void* const* d_in, const int* in_sizes, int n_in,
                              void* d_out, int out_size, void* d_ws, size_t ws_size,
                              hipStream_t stream) {
    const float* xyz = (const float*)d_in[0];
    int* out = (int*)d_out;
    char* ws = (char*)d_ws;

    float* ub0 = (float*)(ws + 0);       float* ub1 = (float*)(ws + 65536);
    float* cd0 = (float*)(ws + 131072);  float* cd1 = (float*)(ws + 196608);
    int*   ui0 = (int*)  (ws + 262144);  int*   ui1 = (int*)  (ws + 327680);
    float* px0 = (float*)(ws + 393216);  float* px1 = (float*)(ws + 458752);
    float* py0 = (float*)(ws + 524288);  float* py1 = (float*)(ws + 589824);
    float* pz0 = (float*)(ws + 655360);  float* pz1 = (float*)(ws + 720896);
    float4* sel = (float4*)(ws + 786432);                       // 10240 B
    unsigned long long* win = (unsigned long long*)(ws + 796672); // 81920 B

    hipMemsetAsync(win, 0, NPOINT * NB * 16 * sizeof(unsigned long long), stream);

    dim3 gridA(QN, NB), gridB(GB, NB), block(TPB);
    fps_scan1<<<gridA, block, 0, stream>>>(xyz, out, sel, ub0, cd0, ui0,
                                           px0, py0, pz0, win);
    fps_step<2><<<gridB, block, 0, stream>>>(xyz, out, sel, ub0, cd0, ui0, px0, py0, pz0,
                                             ub1, cd1, ui1, px1, py1, pz1, win);
    fps_step<3><<<gridB, block, 0, stream>>>(xyz, out, sel, ub1, cd1, ui1, px1, py1, pz1,
                                             ub0, cd0, ui0, px0, py0, pz0, win);
    fps_step<4><<<gridB, block, 0, stream>>>(xyz, out, sel, ub0, cd0, ui0, px0, py0, pz0,
                                             ub1, cd1, ui1, px1, py1, pz1, win);
    fps_step<5><<<gridB, block, 0, stream>>>(xyz, out, sel, ub1, cd1, ui1, px1, py1, pz1,
                                             ub0, cd0, ui0, px0, py0, pz0, win);
    fps_step<6><<<gridB, block, 0, stream>>>(xyz, out, sel, ub0, cd0, ui0, px0, py0, pz0,
                                             ub1, cd1, ui1, px1, py1, pz1, win);
    fps_step<7><<<gridB, block, 0, stream>>>(xyz, out, sel, ub1, cd1, ui1, px1, py1, pz1,
                                             ub0, cd0, ui0, px0, py0, pz0, win);
    fps_step<8><<<gridB, block, 0, stream>>>(xyz, out, sel, ub0, cd0, ui0, px0, py0, pz0,
                                             ub1, cd1, ui1, px1, py1, pz1, win);
    fps_step<9><<<gridB, block, 0, stream>>>(xyz, out, sel, ub1, cd1, ui1, px1, py1, pz1,
                                             ub0, cd0, ui0, px0, py0, pz0, win);
    fps_final<<<dim3(1), dim3(64), 0, stream>>>(win, out);
}